// Round 11
// baseline (525.993 us; speedup 1.0000x reference)
//
#include <hip/hip_runtime.h>
#include <hip/hip_bf16.h>

typedef __bf16 bf16x8 __attribute__((ext_vector_type(8)));
typedef float  f32x4  __attribute__((ext_vector_type(4)));

#define DEV static __device__ __forceinline__

DEV float bf2f(ushort u) { unsigned x = ((unsigned)u) << 16; return __uint_as_float(x); }
DEV ushort f2bf(float f) {
    unsigned u = __float_as_uint(f);
    unsigned r = (u + 0x7FFFu + ((u >> 16) & 1u)) >> 16;  // RNE
    return (ushort)r;
}

// ---------------- fp32 -> bf16 weight conversion (one-time, tiny) ----------------
__global__ __launch_bounds__(256) void f2bf_kernel(
    const float* __restrict__ src, ushort* __restrict__ dst)
{
    int i = (blockIdx.x * 256 + threadIdx.x) * 4;
    float4 v = *(const float4*)(src + i);
    ushort4 o;
    o.x = f2bf(v.x); o.y = f2bf(v.y); o.z = f2bf(v.z); o.w = f2bf(v.w);
    *(ushort4*)(dst + i) = o;
}

// ---------------- box filter: B[g][br][bc][256] fp32, br,bc in [0,65) ----------------
__global__ __launch_bounds__(256) void box_kernel(
    const float* __restrict__ x,   // [8][256][64][64] fp32
    float* __restrict__ B)         // [8][65][65][256] fp32
{
    int br = blockIdx.x % 65; int g = blockIdx.x / 65;
    const float* xg = x + (size_t)g * 256 * 4096;
    float* Bg = B + (size_t)g * 65 * 65 * 256;
    const int r0 = max(br - 1, 0) * 64;
    const int r1 = min(br, 63) * 64;
    __shared__ float s[128][65];
    const int wl = threadIdx.x & 63, cq = threadIdx.x >> 6;   // load mapping
    const int c2 = threadIdx.x & 127, bh = threadIdx.x >> 7;  // store mapping
    for (int half = 0; half < 2; ++half) {
#pragma unroll 4
        for (int it = 0; it < 32; ++it) {
            int cl_ = it * 4 + cq;
            const float* xp = xg + (size_t)(half * 128 + cl_) * 4096;
            s[cl_][wl] = xp[r0 + wl] + xp[r1 + wl];
        }
        __syncthreads();
        for (int bc = bh; bc < 65; bc += 2) {
            float v = 0.25f * (s[c2][max(bc - 1, 0)] + s[c2][min(bc, 63)]);
            Bg[((size_t)br * 65 + bc) * 256 + half * 128 + c2] = v;
        }
        __syncthreads();
    }
}

// ---------------- pool gather + depthwise 3x3 + residual ----------------
template<int K, int L>
__global__ __launch_bounds__(256) void pool_kernel(
    const float* __restrict__ B,    // [8][65][65][256] fp32
    const float* __restrict__ w9,   // [256][9] fp32
    const float* __restrict__ bias, // [256] fp32
    ushort* __restrict__ y)         // bf16 out
{
    constexpr int HF = K / 2;
    const int pk = blockIdx.x;
    const int lw = pk % L; int t = pk / L; const int lh = t % L; const int g = t / L;
    const int c = threadIdx.x;
    const float* Bg = B + (size_t)g * 65 * 65 * 256 + c;
    float pool[K][K];
#pragma unroll
    for (int p = 0; p < K; ++p) {
        const int br = lh * 4 + p + (p >= HF ? 1 : 0);
#pragma unroll
        for (int q = 0; q < K; ++q) {
            const int bc = lw * 4 + q + (q >= HF ? 1 : 0);
            pool[p][q] = Bg[((size_t)br * 65 + bc) * 256];
        }
    }
    float wv[9];
#pragma unroll
    for (int i = 0; i < 9; ++i) wv[i] = w9[c * 9 + i];
    const float bv = bias[c];
    ushort* yp = y + (size_t)pk * (K * K) * 256 + c;
#pragma unroll
    for (int p = 0; p < K; ++p) {
#pragma unroll
        for (int q = 0; q < K; ++q) {
            float a = pool[p][q] + bv;   // residual + conv bias
#pragma unroll
            for (int dp = -1; dp <= 1; ++dp) {
#pragma unroll
                for (int dq = -1; dq <= 1; ++dq) {
                    int pp = p + dp, qq = q + dq;
                    if (pp >= 0 && pp < K && qq >= 0 && qq < K)
                        a += wv[(dp + 1) * 3 + (dq + 1)] * pool[pp][qq];
                }
            }
            yp[(p * K + q) * 256] = f2bf(a);
        }
    }
}

// ---------------- GEMM 64x64 tiles, XCD-aware swizzle + LDS XOR swizzle ----------------
template<int OC, int EPI, int K, int L, int RT>
__global__ __launch_bounds__(256) void gemm_kernel(
    const ushort* __restrict__ act,  // [rows][256] bf16
    const ushort* __restrict__ w,    // [OC][256]  bf16
    const float* __restrict__ bias,  // [OC] fp32
    ushort* __restrict__ out_bf)
{
    __shared__ __attribute__((aligned(16))) ushort As[64][40];
    __shared__ __attribute__((aligned(16))) ushort Ws[64][40];
    constexpr int NT = OC / 64;
    const int id  = blockIdx.x;
    const int xc  = id & 7;
    const int ctb = (id >> 3) % NT;
    const int tt  = id / (8 * NT);
    const int rowt = tt * 8 + xc;
    if (rowt >= RT) return;
    const int tid  = threadIdx.x;
    const int n0   = rowt * 64;
    const int ch0  = ctb * 64;
    const int wv   = tid >> 6, lane = tid & 63;
    const int l15  = lane & 15, quad = lane >> 4;
    const int ar   = tid >> 2, g = tid & 3;
    const int scol = ((g ^ (ar & 3)) * 8);     // swizzled staging col
    f32x4 acc[4] = {};

    const ushort* aptr = act + (size_t)(n0 + ar) * 256 + g * 8;
    const ushort* wptr = w   + (size_t)(ch0 + ar) * 256 + g * 8;
    const int mrow = wv * 16 + l15;
    const int aswz = ((quad ^ (mrow & 3)) * 8);
    for (int k0 = 0; k0 < 256; k0 += 32) {
        *(uint4*)&As[ar][scol] = *(const uint4*)(aptr + k0);
        *(uint4*)&Ws[ar][scol] = *(const uint4*)(wptr + k0);
        __syncthreads();
        bf16x8 af = *(const bf16x8*)&As[mrow][aswz];
#pragma unroll
        for (int mt = 0; mt < 4; ++mt) {
            const int brow = mt * 16 + l15;
            bf16x8 bfv = *(const bf16x8*)&Ws[brow][((quad ^ (brow & 3)) * 8)];
            acc[mt] = __builtin_amdgcn_mfma_f32_16x16x32_bf16(af, bfv, acc[mt], 0, 0, 0);
        }
        __syncthreads();
    }
    const int rbase = wv * 16 + quad * 4;
#pragma unroll
    for (int mt = 0; mt < 4; ++mt) {
        int ch = ch0 + mt * 16 + l15;
        float bv = bias[ch];
#pragma unroll
        for (int r = 0; r < 4; ++r) {
            int n = n0 + rbase + r;
            float val = acc[mt][r] + bv;
            if (EPI == 0) {
                out_bf[(size_t)n * OC + ch] = f2bf(val);
            } else {
                constexpr int K2 = K * K;
                constexpr int LL = L * L;
                int b_g   = n >> (K == 8 ? 6 : 4);
                int pq    = n & (K2 - 1);
                int gl    = b_g / LL;
                int b_loc = b_g - gl * LL;
                int f = (b_loc * 256 + ch) * K2 + pq;
                out_bf[(size_t)gl * (256 * K2 * LL) + f] = f2bf(val);
            }
        }
    }
}

// ---------------- FUSED qkv-GEMM + MFMA attention for K=8 ----------------
// block = (patch b, head-pair hp); 256 thr = 4 waves.
// Phase 1: wave w computes qkv chs [hp*256 + w*64, +64) for all 64 rows -> LDS qkvt.
// Phase 2: wave w = (head hh=w>>1, strip-set ww=w&1) does attention from LDS.
__global__ __launch_bounds__(256) void fused_attn8_kernel(
    const ushort* __restrict__ y,    // [patches*64][256] bf16
    const ushort* __restrict__ qw,   // [512][256] bf16
    const float* __restrict__ qb,    // [512] fp32
    const float* __restrict__ pe_w,  // [256][9] fp32
    const float* __restrict__ pe_b,  // [256] fp32
    ushort* __restrict__ o_out)      // [patches*64][256] bf16
{
    constexpr float SCALE = 0.17677669529663687f;  // 32^-0.5
    __shared__ __attribute__((aligned(16))) ushort qkvt[64][264];  // 33.8 KB, stride 528B (16B-mult, 2-way banks)
    __shared__ __attribute__((aligned(16))) ushort Pl[2][64][72];  // PEsh, then P
    __shared__ __attribute__((aligned(16))) ushort Vt[2][64][72];
    __shared__ __attribute__((aligned(16))) ushort wsh[9][128];
    __shared__ float bsh[128];
    const int tid  = threadIdx.x;
    const int lane = tid & 63;
    const int w    = tid >> 6;
    const int b    = blockIdx.x >> 1;
    const int hp   = blockIdx.x & 1;
    const int l15  = lane & 15, quad = lane >> 4;
    const ushort* ybase = y + (size_t)b * 64 * 256;

    // ---- stage dwconv weights for channels [hp*128, hp*128+128)
    const int cbase = hp * 128;
    for (int idx = tid; idx < 9 * 128; idx += 256) {
        int tap = idx >> 7, cl = idx & 127;
        wsh[tap][cl] = f2bf(pe_w[(cbase + cl) * 9 + tap]);
    }
    if (tid < 128) bsh[tid] = pe_b[cbase + tid];

    // ---- Phase 1: qkv GEMM, wave w -> global chs chg..chg+64
    {
        const int chg = hp * 256 + w * 64;
        f32x4 acc[4][4] = {};
        for (int kc = 0; kc < 8; ++kc) {
            bf16x8 af[4], bfr[4];
#pragma unroll
            for (int rs = 0; rs < 4; ++rs)
                af[rs] = *(const bf16x8*)(ybase + (size_t)(rs * 16 + l15) * 256 + kc * 32 + quad * 8);
#pragma unroll
            for (int cs = 0; cs < 4; ++cs)
                bfr[cs] = *(const bf16x8*)(qw + (size_t)(chg + cs * 16 + l15) * 256 + kc * 32 + quad * 8);
#pragma unroll
            for (int rs = 0; rs < 4; ++rs)
#pragma unroll
                for (int cs = 0; cs < 4; ++cs)
                    acc[rs][cs] = __builtin_amdgcn_mfma_f32_16x16x32_bf16(af[rs], bfr[cs], acc[rs][cs], 0, 0, 0);
        }
#pragma unroll
        for (int cs = 0; cs < 4; ++cs) {
            int chl = w * 64 + cs * 16 + l15;     // local ch within hp half (0..255)
            float bv = qb[hp * 256 + chl];
#pragma unroll
            for (int rs = 0; rs < 4; ++rs)
#pragma unroll
                for (int r = 0; r < 4; ++r)
                    qkvt[rs * 16 + quad * 4 + r][chl] = f2bf(acc[rs][cs][r] + bv);
        }
    }
    __syncthreads();   // qkvt visible

    const int hh = w >> 1, ww = w & 1;
    const int hl = hh * 128;

    // ---- V transpose into Vt[hh][d][m] (this wave: d in [ww*32, ww*32+32))
    {
        const int m = lane;
        const int d0 = ww * 32;
#pragma unroll
        for (int t = 0; t < 4; ++t) {
            uint4 vv = *(const uint4*)&qkvt[m][hl + 64 + d0 + t * 8];
            unsigned u[4] = {vv.x, vv.y, vv.z, vv.w};
#pragma unroll
            for (int e = 0; e < 4; ++e) {
                Vt[hh][d0 + t * 8 + e * 2][m]     = (ushort)(u[e] & 0xFFFF);
                Vt[hh][d0 + t * 8 + e * 2 + 1][m] = (ushort)(u[e] >> 16);
            }
        }
    }

    // ---- S = Q^T K (from LDS qkvt)
    bf16x8 fq[2];
#pragma unroll
    for (int s = 0; s < 2; ++s)
        fq[s] = *(const bf16x8*)&qkvt[(ww + 2 * s) * 16 + l15][hl + quad * 8];
    f32x4 S[2][4];
#pragma unroll
    for (int mt = 0; mt < 4; ++mt) {
        bf16x8 fk = *(const bf16x8*)&qkvt[mt * 16 + l15][hl + 32 + quad * 8];
#pragma unroll
        for (int s = 0; s < 2; ++s) {
            f32x4 z = {0.f, 0.f, 0.f, 0.f};
            S[s][mt] = __builtin_amdgcn_mfma_f32_16x16x32_bf16(fq[s], fk, z, 0, 0, 0);
        }
    }

    // ---- PE pre-pass: PEsh[hh2][n][d] = bias + dwconv3(V) (V rows from qkvt)
    {
        const int d8  = (tid & 7) * 8;
        const int nb  = (tid >> 3) & 15;
        const int hh2 = tid >> 7;
        const int cl0 = hh2 * 64 + d8;
        float pb[8];
#pragma unroll
        for (int e = 0; e < 8; ++e) pb[e] = bsh[cl0 + e];
        uint4 wu[9];
#pragma unroll
        for (int tap = 0; tap < 9; ++tap) wu[tap] = *(const uint4*)&wsh[tap][cl0];
#pragma unroll
        for (int it = 0; it < 4; ++it) {
            const int n = nb + 16 * it;
            const int p = n >> 3, q = n & 7;
            float pe[8];
#pragma unroll
            for (int e = 0; e < 8; ++e) pe[e] = pb[e];
#pragma unroll
            for (int dp = -1; dp <= 1; ++dp) {
#pragma unroll
                for (int dq = -1; dq <= 1; ++dq) {
                    const int pp = p + dp, qq = q + dq;
                    if (pp >= 0 && pp < 8 && qq >= 0 && qq < 8) {
                        const int tap = (dp + 1) * 3 + (dq + 1);
                        uint4 vv = *(const uint4*)&qkvt[pp * 8 + qq][hh2 * 128 + 64 + d8];
                        unsigned uv[4] = {vv.x, vv.y, vv.z, vv.w};
                        unsigned uw[4] = {wu[tap].x, wu[tap].y, wu[tap].z, wu[tap].w};
#pragma unroll
                        for (int e2 = 0; e2 < 4; ++e2) {
                            float vlo = __uint_as_float(uv[e2] << 16);
                            float vhi = __uint_as_float(uv[e2] & 0xFFFF0000u);
                            float wlo = __uint_as_float(uw[e2] << 16);
                            float whi = __uint_as_float(uw[e2] & 0xFFFF0000u);
                            pe[2 * e2]     += wlo * vlo;
                            pe[2 * e2 + 1] += whi * vhi;
                        }
                    }
                }
            }
            ushort pk[8];
#pragma unroll
            for (int e = 0; e < 8; ++e) pk[e] = f2bf(pe[e]);
            *(uint4*)&Pl[hh2][n][d8] = *(const uint4*)pk;
        }
    }
    __syncthreads();   // Vt + PEsh visible

    // ---- O acc init from PEsh
    f32x4 O[2][4];
#pragma unroll
    for (int s = 0; s < 2; ++s)
#pragma unroll
        for (int dt = 0; dt < 4; ++dt)
#pragma unroll
            for (int r = 0; r < 4; ++r)
                O[s][dt][r] = bf2f(Pl[hh][(ww + 2 * s) * 16 + quad * 4 + r][dt * 16 + l15]);

    // ---- softmax (in-register, 16-lane shuffle groups)
#pragma unroll
    for (int s = 0; s < 2; ++s) {
#pragma unroll
        for (int r = 0; r < 4; ++r) {
            float mx = -1e30f;
#pragma unroll
            for (int mt = 0; mt < 4; ++mt) { S[s][mt][r] *= SCALE; mx = fmaxf(mx, S[s][mt][r]); }
            mx = fmaxf(mx, __shfl_xor(mx, 1));
            mx = fmaxf(mx, __shfl_xor(mx, 2));
            mx = fmaxf(mx, __shfl_xor(mx, 4));
            mx = fmaxf(mx, __shfl_xor(mx, 8));
            float sum = 0.f;
#pragma unroll
            for (int mt = 0; mt < 4; ++mt) { float e = __expf(S[s][mt][r] - mx); S[s][mt][r] = e; sum += e; }
            sum += __shfl_xor(sum, 1);
            sum += __shfl_xor(sum, 2);
            sum += __shfl_xor(sum, 4);
            sum += __shfl_xor(sum, 8);
            float inv = 1.f / sum;
#pragma unroll
            for (int mt = 0; mt < 4; ++mt) S[s][mt][r] *= inv;
        }
    }
    __syncthreads();   // all PEsh reads done

    // ---- write P -> Pl
#pragma unroll
    for (int s = 0; s < 2; ++s)
#pragma unroll
        for (int r = 0; r < 4; ++r) {
            int n = (ww + 2 * s) * 16 + quad * 4 + r;
#pragma unroll
            for (int mt = 0; mt < 4; ++mt)
                Pl[hh][n][mt * 16 + l15] = f2bf(S[s][mt][r]);
        }
    __syncthreads();   // Pl visible

    // ---- O += P · V^T
#pragma unroll
    for (int ks = 0; ks < 2; ++ks) {
        bf16x8 fp[2], fv[4];
#pragma unroll
        for (int s = 0; s < 2; ++s)
            fp[s] = *(const bf16x8*)&Pl[hh][(ww + 2 * s) * 16 + l15][ks * 32 + quad * 8];
#pragma unroll
        for (int dt = 0; dt < 4; ++dt)
            fv[dt] = *(const bf16x8*)&Vt[hh][dt * 16 + l15][ks * 32 + quad * 8];
#pragma unroll
        for (int s = 0; s < 2; ++s)
#pragma unroll
            for (int dt = 0; dt < 4; ++dt)
                O[s][dt] = __builtin_amdgcn_mfma_f32_16x16x32_bf16(fp[s], fv[dt], O[s][dt], 0, 0, 0);
    }
    // ---- write o_out[n][c], c = hp*128 + hh*64 + dt*16 + l15
#pragma unroll
    for (int s = 0; s < 2; ++s) {
#pragma unroll
        for (int r = 0; r < 4; ++r) {
            int n = (ww + 2 * s) * 16 + quad * 4 + r;
            ushort* dst = o_out + (size_t)(b * 64 + n) * 256 + hp * 128 + hh * 64;
#pragma unroll
            for (int dt = 0; dt < 4; ++dt)
                dst[dt * 16 + l15] = f2bf(O[s][dt][r]);
        }
    }
}

// ---------------- scalar attention (used for K=4) ----------------
template<int K>
__global__ __launch_bounds__(256) void attn_kernel(
    const ushort* __restrict__ qkv,
    const float* __restrict__ pe_w,
    const float* __restrict__ pe_b,
    ushort* __restrict__ o_out)
{
    constexpr int NSP = K * K;
    constexpr float SCALE = 0.17677669529663687f;
    __shared__ float q_s[32][NSP];
    __shared__ float k_s[32][NSP];
    __shared__ float v_s[64][NSP + 1];
    __shared__ float S[NSP][NSP + 1];
    const int tid = threadIdx.x;
    const int h = blockIdx.x & 3;
    const int b = blockIdx.x >> 2;
    {
        int n0 = tid >> 4;
        int rr = (tid & 15) * 8;
        for (int nb = 0; nb < NSP; nb += 16) {
            int n = nb + n0;
            const ushort* src = qkv + (size_t)(b * NSP + n) * 512 + h * 128 + rr;
            uint4 pk = *(const uint4*)src;
            ushort us[8];
            *(uint4*)us = pk;
#pragma unroll
            for (int j = 0; j < 8; ++j) {
                int r = rr + j;
                float f = bf2f(us[j]);
                if (r < 32) q_s[r][n] = f * SCALE;
                else if (r < 64) k_s[r - 32][n] = f;
                else v_s[r - 64][n] = f;
            }
        }
    }
    __syncthreads();
    for (int idx = tid; idx < NSP * NSP; idx += 256) {
        int n = idx / NSP, m = idx % NSP;
        float a = 0.f;
#pragma unroll
        for (int d = 0; d < 32; ++d) a += q_s[d][n] * k_s[d][m];
        S[n][m] = a;
    }
    __syncthreads();
    for (int n = tid; n < NSP; n += 256) {
        float mx = -1e30f;
        for (int m = 0; m < NSP; ++m) mx = fmaxf(mx, S[n][m]);
        float sum = 0.f;
        for (int m = 0; m < NSP; ++m) { float e = __expf(S[n][m] - mx); S[n][m] = e; sum += e; }
        float inv = 1.f / sum;
        for (int m = 0; m < NSP; ++m) S[n][m] *= inv;
    }
    __syncthreads();
    for (int idx = tid; idx < 64 * NSP; idx += 256) {
        int d = idx & 63, n = idx >> 6;
        float a = 0.f;
        for (int m = 0; m < NSP; ++m) a += v_s[d][m] * S[n][m];
        int c = h * 64 + d;
        int p = n / K, q = n % K;
        float pe = pe_b[c];
        const float* wc = pe_w + c * 9;
#pragma unroll
        for (int dp = -1; dp <= 1; ++dp) {
#pragma unroll
            for (int dq = -1; dq <= 1; ++dq) {
                int pp = p + dp, qq = q + dq;
                if (pp >= 0 && pp < K && qq >= 0 && qq < K)
                    pe += wc[(dp + 1) * 3 + (dq + 1)] * v_s[d][pp * K + qq];
            }
        }
        o_out[(size_t)(b * NSP + n) * 256 + c] = f2bf(a + pe);
    }
}

// ---------------- final: out = (x + fold8(s8) + fold4(s4)) / 3 ----------------
__global__ __launch_bounds__(256) void final_kernel(
    const float* __restrict__ x,
    const ushort* __restrict__ s8,
    const ushort* __restrict__ s4,
    float* __restrict__ out)
{
    const int c2 = blockIdx.x & 255;
    const int g  = blockIdx.x >> 8;
    const ushort* s8g = s8 + (size_t)g * (256 * 64 * 225);
    const ushort* s4g = s4 + (size_t)g * (256 * 16 * 256);
    const float third = 1.f / 3.f;
#pragma unroll 2
    for (int it = 0; it < 16; ++it) {
        int pix = it * 256 + threadIdx.x;       // h*64 + w
        int h = pix >> 6, w = pix & 63;
        int f4 = ((((c2 * 4 + (h & 3)) * 4 + (w & 3)) * 16 + (h >> 2)) * 16) + (w >> 2);
        float v4 = bf2f(s4g[f4]);
        int lh_lo = (h >= 8) ? ((h - 4) >> 2) : 0, lh_hi = min(14, h >> 2);
        int lw_lo = (w >= 8) ? ((w - 4) >> 2) : 0, lw_hi = min(14, w >> 2);
        float v8 = 0.f;
        for (int lh2 = lh_lo; lh2 <= lh_hi; ++lh2) {
            int p2 = h - lh2 * 4;
            for (int lw2 = lw_lo; lw2 <= lw_hi; ++lw2) {
                int q2 = w - lw2 * 4;
                int f8 = (((c2 * 8 + p2) * 8 + q2) * 15 + lh2) * 15 + lw2;
                v8 += bf2f(s8g[f8]);
            }
        }
        float inv = 1.f / (float)((lh_hi - lh_lo + 1) * (lw_hi - lw_lo + 1));
        size_t off = ((size_t)(g * 256 + c2)) * 4096 + pix;
        out[off] = (x[off] + v8 * inv + v4) * third;
    }
}

extern "C" void kernel_launch(void* const* d_in, const int* in_sizes, int n_in,
                              void* d_out, int out_size, void* d_ws, size_t ws_size,
                              hipStream_t stream)
{
    const float* x      = (const float*)d_in[0];
    const float* qkv_w  = (const float*)d_in[1];
    const float* qkv_b  = (const float*)d_in[2];
    const float* proj_w = (const float*)d_in[3];
    const float* proj_b = (const float*)d_in[4];
    const float* apw    = (const float*)d_in[5];
    const float* apb    = (const float*)d_in[6];
    const float* dpw    = (const float*)d_in[7];
    const float* dpb    = (const float*)d_in[8];
    float* out = (float*)d_out;

    // Layout: [s8 59M][s4 16.8M][wq .26M][wp .13M][arena 118M] = 194.1 MB total.
    // Arena: O8 @0 (59M), Y8 @59M (59M). Phase-1 overlays (dead before their regions'
    // writers): B @0 (34.6M, last read by pool8), y4 @34.6M (16.8M), q4 @51.4M (33.6M).
    const size_t S8_B = 8ull * 225 * 256 * 64 * 2;    // 58,982,400
    const size_t S4_B = 8ull * 256 * 256 * 16 * 2;    // 16,777,216
    const size_t WQ_B = 512ull * 256 * 2;
    const size_t WP_B = 256ull * 256 * 2;
    const size_t AR_B = 2ull * 58982400;              // O8 + Y8
    if (ws_size < S8_B + S4_B + WQ_B + WP_B + AR_B) {
        hipMemsetAsync(d_out, 0x46, 4, stream);  // finite sentinel: ws too small
        return;
    }
    char* base = (char*)d_ws;
    ushort* s8    = (ushort*)base;
    ushort* s4    = (ushort*)(base + S8_B);
    ushort* qw_bf = (ushort*)(base + S8_B + S4_B);
    ushort* pw_bf = (ushort*)(base + S8_B + S4_B + WQ_B);
    char*  arena  = base + S8_B + S4_B + WQ_B + WP_B;
    ushort* o8    = (ushort*)(arena);
    ushort* y8    = (ushort*)(arena + 58982400);
    float*  Bbuf  = (float*)(arena);                   // aliases o8 (dead before o8 written)
    ushort* y4    = (ushort*)(arena + 34611200);
    ushort* q4    = (ushort*)(arena + 51388416);

    f2bf_kernel<<<128, 256, 0, stream>>>(qkv_w, qw_bf);
    f2bf_kernel<<<64, 256, 0, stream>>>(proj_w, pw_bf);
    box_kernel<<<8 * 65, 256, 0, stream>>>(x, Bbuf);

    // K=4 chain first (L=16, 2048 patches, 32768 rows = 512 row-tiles)
    pool_kernel<4, 16><<<8 * 256, 256, 0, stream>>>(Bbuf, dpw, dpb, y4);
    gemm_kernel<512, 0, 4, 16, 512><<<4096, 256, 0, stream>>>(y4, qw_bf, qkv_b, q4);
    attn_kernel<4><<<8 * 256 * 4, 256, 0, stream>>>(q4, apw, apb, y4);
    gemm_kernel<256, 1, 4, 16, 512><<<2048, 256, 0, stream>>>(y4, pw_bf, proj_b, s4);

    // K=8 chain, full batch (L=15, 1800 patches, 115200 rows = 1800 row-tiles)
    pool_kernel<8, 15><<<8 * 225, 256, 0, stream>>>(Bbuf, dpw, dpb, y8);
    fused_attn8_kernel<<<1800 * 2, 256, 0, stream>>>(y8, qw_bf, qkv_b, apw, apb, o8);
    gemm_kernel<256, 1, 8, 15, 1800><<<7200, 256, 0, stream>>>(o8, pw_bf, proj_b, s8);

    final_kernel<<<2048, 256, 0, stream>>>(x, s8, s4, out);
}

// Round 12
// 483.024 us; speedup vs baseline: 1.0890x; 1.0890x over previous
//
#include <hip/hip_runtime.h>
#include <hip/hip_bf16.h>

typedef __bf16 bf16x8 __attribute__((ext_vector_type(8)));
typedef float  f32x4  __attribute__((ext_vector_type(4)));

#define DEV static __device__ __forceinline__

DEV float bf2f(ushort u) { unsigned x = ((unsigned)u) << 16; return __uint_as_float(x); }
DEV ushort f2bf(float f) {
    unsigned u = __float_as_uint(f);
    unsigned r = (u + 0x7FFFu + ((u >> 16) & 1u)) >> 16;  // RNE
    return (ushort)r;
}

// ---------------- fp32 -> bf16 weight conversion (one-time, tiny) ----------------
__global__ __launch_bounds__(256) void f2bf_kernel(
    const float* __restrict__ src, ushort* __restrict__ dst)
{
    int i = (blockIdx.x * 256 + threadIdx.x) * 4;
    float4 v = *(const float4*)(src + i);
    ushort4 o;
    o.x = f2bf(v.x); o.y = f2bf(v.y); o.z = f2bf(v.z); o.w = f2bf(v.w);
    *(ushort4*)(dst + i) = o;
}

// ---------------- box filter: B[g][br][bc][256] bf16, br,bc in [0,65) ----------------
__global__ __launch_bounds__(256) void box_kernel(
    const float* __restrict__ x,   // [8][256][64][64] fp32
    ushort* __restrict__ B)        // [8][65][65][256] bf16
{
    int br = blockIdx.x % 65; int g = blockIdx.x / 65;
    const float* xg = x + (size_t)g * 256 * 4096;
    ushort* Bg = B + (size_t)g * 65 * 65 * 256;
    const int r0 = max(br - 1, 0) * 64;
    const int r1 = min(br, 63) * 64;
    __shared__ float s[128][65];
    const int wl = threadIdx.x & 63, cq = threadIdx.x >> 6;   // load mapping
    const int c2 = threadIdx.x & 127, bh = threadIdx.x >> 7;  // store mapping
    for (int half = 0; half < 2; ++half) {
#pragma unroll 4
        for (int it = 0; it < 32; ++it) {
            int cl_ = it * 4 + cq;
            const float* xp = xg + (size_t)(half * 128 + cl_) * 4096;
            s[cl_][wl] = xp[r0 + wl] + xp[r1 + wl];
        }
        __syncthreads();
        for (int bc = bh; bc < 65; bc += 2) {
            float v = 0.25f * (s[c2][max(bc - 1, 0)] + s[c2][min(bc, 63)]);
            Bg[((size_t)br * 65 + bc) * 256 + half * 128 + c2] = f2bf(v);
        }
        __syncthreads();
    }
}

// ---------------- pool gather + depthwise 3x3 + residual ----------------
template<int K, int L>
__global__ __launch_bounds__(256) void pool_kernel(
    const ushort* __restrict__ B,   // [8][65][65][256] bf16
    const float* __restrict__ w9,   // [256][9] fp32
    const float* __restrict__ bias, // [256] fp32
    ushort* __restrict__ y)         // bf16 out
{
    constexpr int HF = K / 2;
    const int pk = blockIdx.x;
    const int lw = pk % L; int t = pk / L; const int lh = t % L; const int g = t / L;
    const int c = threadIdx.x;
    const ushort* Bg = B + (size_t)g * 65 * 65 * 256 + c;
    float pool[K][K];
#pragma unroll
    for (int p = 0; p < K; ++p) {
        const int br = lh * 4 + p + (p >= HF ? 1 : 0);
#pragma unroll
        for (int q = 0; q < K; ++q) {
            const int bc = lw * 4 + q + (q >= HF ? 1 : 0);
            pool[p][q] = bf2f(Bg[((size_t)br * 65 + bc) * 256]);
        }
    }
    float wv[9];
#pragma unroll
    for (int i = 0; i < 9; ++i) wv[i] = w9[c * 9 + i];
    const float bv = bias[c];
    ushort* yp = y + (size_t)pk * (K * K) * 256 + c;
#pragma unroll
    for (int p = 0; p < K; ++p) {
#pragma unroll
        for (int q = 0; q < K; ++q) {
            float a = pool[p][q] + bv;   // residual + conv bias
#pragma unroll
            for (int dp = -1; dp <= 1; ++dp) {
#pragma unroll
                for (int dq = -1; dq <= 1; ++dq) {
                    int pp = p + dp, qq = q + dq;
                    if (pp >= 0 && pp < K && qq >= 0 && qq < K)
                        a += wv[(dp + 1) * 3 + (dq + 1)] * pool[pp][qq];
                }
            }
            yp[(p * K + q) * 256] = f2bf(a);
        }
    }
}

// ---------------- GEMM 64x64 tiles, XCD-aware swizzle + LDS XOR swizzle ----------------
template<int OC, int EPI, int K, int L, int RT>
__global__ __launch_bounds__(256) void gemm_kernel(
    const ushort* __restrict__ act,  // [rows][256] bf16
    const ushort* __restrict__ w,    // [OC][256]  bf16
    const float* __restrict__ bias,  // [OC] fp32
    ushort* __restrict__ out_bf)
{
    __shared__ __attribute__((aligned(16))) ushort As[64][40];
    __shared__ __attribute__((aligned(16))) ushort Ws[64][40];
    constexpr int NT = OC / 64;
    const int id  = blockIdx.x;
    const int xc  = id & 7;
    const int ctb = (id >> 3) % NT;
    const int tt  = id / (8 * NT);
    const int rowt = tt * 8 + xc;
    if (rowt >= RT) return;
    const int tid  = threadIdx.x;
    const int n0   = rowt * 64;
    const int ch0  = ctb * 64;
    const int wv   = tid >> 6, lane = tid & 63;
    const int l15  = lane & 15, quad = lane >> 4;
    const int ar   = tid >> 2, g = tid & 3;
    const int scol = ((g ^ (ar & 3)) * 8);     // swizzled staging col
    f32x4 acc[4] = {};

    const ushort* aptr = act + (size_t)(n0 + ar) * 256 + g * 8;
    const ushort* wptr = w   + (size_t)(ch0 + ar) * 256 + g * 8;
    const int mrow = wv * 16 + l15;
    const int aswz = ((quad ^ (mrow & 3)) * 8);
    for (int k0 = 0; k0 < 256; k0 += 32) {
        *(uint4*)&As[ar][scol] = *(const uint4*)(aptr + k0);
        *(uint4*)&Ws[ar][scol] = *(const uint4*)(wptr + k0);
        __syncthreads();
        bf16x8 af = *(const bf16x8*)&As[mrow][aswz];
#pragma unroll
        for (int mt = 0; mt < 4; ++mt) {
            const int brow = mt * 16 + l15;
            bf16x8 bfv = *(const bf16x8*)&Ws[brow][((quad ^ (brow & 3)) * 8)];
            acc[mt] = __builtin_amdgcn_mfma_f32_16x16x32_bf16(af, bfv, acc[mt], 0, 0, 0);
        }
        __syncthreads();
    }
    const int rbase = wv * 16 + quad * 4;
#pragma unroll
    for (int mt = 0; mt < 4; ++mt) {
        int ch = ch0 + mt * 16 + l15;
        float bv = bias[ch];
#pragma unroll
        for (int r = 0; r < 4; ++r) {
            int n = n0 + rbase + r;
            float val = acc[mt][r] + bv;
            if (EPI == 0) {
                out_bf[(size_t)n * OC + ch] = f2bf(val);
            } else {
                constexpr int K2 = K * K;
                constexpr int LL = L * L;
                int b_g   = n >> (K == 8 ? 6 : 4);
                int pq    = n & (K2 - 1);
                int gl    = b_g / LL;
                int b_loc = b_g - gl * LL;
                int f = (b_loc * 256 + ch) * K2 + pq;
                out_bf[(size_t)gl * (256 * K2 * LL) + f] = f2bf(val);
            }
        }
    }
}

// ---------------- MFMA attention for K=8 (NSP=64): block = 1 patch, 2 heads ----------------
__global__ __launch_bounds__(256) void attn8_mfma_kernel(
    const ushort* __restrict__ qkv,  // [patches*64][512] bf16
    const float* __restrict__ pe_w,  // [256][9] fp32
    const float* __restrict__ pe_b,  // [256] fp32
    ushort* __restrict__ o_out)      // [patches*64][256] bf16
{
    constexpr float SCALE = 0.17677669529663687f;  // 32^-0.5
    __shared__ __attribute__((aligned(16))) ushort Pl[2][64][72];  // PEsh, then P
    __shared__ __attribute__((aligned(16))) ushort Vt[2][64][72];
    __shared__ __attribute__((aligned(16))) ushort wsh[9][128];    // dwconv w, [tap][c-local] bf16
    __shared__ float bsh[128];
    const int tid  = threadIdx.x;
    const int lane = tid & 63;
    const int w    = tid >> 6;
    const int hh   = w >> 1, ww = w & 1;
    const int b    = blockIdx.x >> 1;
    const int hbase = (blockIdx.x & 1) * 2;
    const int cbase = hbase * 64;
    const int h    = hbase + hh;
    const int l15  = lane & 15, quad = lane >> 4;
    const ushort* base = qkv + (size_t)b * 64 * 512 + h * 128;

    for (int idx = tid; idx < 9 * 128; idx += 256) {
        int tap = idx >> 7, cl = idx & 127;
        wsh[tap][cl] = f2bf(pe_w[(cbase + cl) * 9 + tap]);
    }
    if (tid < 128) bsh[tid] = pe_b[cbase + tid];

    {
        const int m = lane;
        const ushort* vsrc = base + (size_t)m * 512 + 64 + ww * 32;
        const int d0 = ww * 32;
#pragma unroll
        for (int t = 0; t < 4; ++t) {
            uint4 vv = *(const uint4*)(vsrc + t * 8);
            unsigned u[4] = {vv.x, vv.y, vv.z, vv.w};
#pragma unroll
            for (int e = 0; e < 4; ++e) {
                Vt[hh][d0 + t * 8 + e * 2][m]     = (ushort)(u[e] & 0xFFFF);
                Vt[hh][d0 + t * 8 + e * 2 + 1][m] = (ushort)(u[e] >> 16);
            }
        }
    }

    bf16x8 fq[2];
#pragma unroll
    for (int s = 0; s < 2; ++s) {
        int n = (ww + 2 * s) * 16 + l15;
        fq[s] = *(const bf16x8*)(base + (size_t)n * 512 + quad * 8);
    }
    f32x4 S[2][4];
#pragma unroll
    for (int mt = 0; mt < 4; ++mt) {
        int m = mt * 16 + l15;
        bf16x8 fk = *(const bf16x8*)(base + (size_t)m * 512 + 32 + quad * 8);
#pragma unroll
        for (int s = 0; s < 2; ++s) {
            f32x4 z = {0.f, 0.f, 0.f, 0.f};
            S[s][mt] = __builtin_amdgcn_mfma_f32_16x16x32_bf16(fq[s], fk, z, 0, 0, 0);
        }
    }
    __syncthreads();   // wsh, bsh, Vt visible

    {
        const int d8  = (tid & 7) * 8;
        const int nb  = (tid >> 3) & 15;
        const int hh2 = tid >> 7;
        const int h2  = hbase + hh2;
        const int cl0 = hh2 * 64 + d8;
        const ushort* vbase = qkv + (size_t)b * 64 * 512 + h2 * 128 + 64 + d8;
        float pb[8];
#pragma unroll
        for (int e = 0; e < 8; ++e) pb[e] = bsh[cl0 + e];
        uint4 wu[9];
#pragma unroll
        for (int tap = 0; tap < 9; ++tap) wu[tap] = *(const uint4*)&wsh[tap][cl0];
#pragma unroll
        for (int it = 0; it < 4; ++it) {
            const int n = nb + 16 * it;
            const int p = n >> 3, q = n & 7;
            float pe[8];
#pragma unroll
            for (int e = 0; e < 8; ++e) pe[e] = pb[e];
#pragma unroll
            for (int dp = -1; dp <= 1; ++dp) {
#pragma unroll
                for (int dq = -1; dq <= 1; ++dq) {
                    const int pp = p + dp, qq = q + dq;
                    if (pp >= 0 && pp < 8 && qq >= 0 && qq < 8) {
                        const int tap = (dp + 1) * 3 + (dq + 1);
                        uint4 vv = *(const uint4*)(vbase + (size_t)(pp * 8 + qq) * 512);
                        unsigned uv[4] = {vv.x, vv.y, vv.z, vv.w};
                        unsigned uw[4] = {wu[tap].x, wu[tap].y, wu[tap].z, wu[tap].w};
#pragma unroll
                        for (int e2 = 0; e2 < 4; ++e2) {
                            float vlo = __uint_as_float(uv[e2] << 16);
                            float vhi = __uint_as_float(uv[e2] & 0xFFFF0000u);
                            float wlo = __uint_as_float(uw[e2] << 16);
                            float whi = __uint_as_float(uw[e2] & 0xFFFF0000u);
                            pe[2 * e2]     += wlo * vlo;
                            pe[2 * e2 + 1] += whi * vhi;
                        }
                    }
                }
            }
            ushort pk[8];
#pragma unroll
            for (int e = 0; e < 8; ++e) pk[e] = f2bf(pe[e]);
            *(uint4*)&Pl[hh2][n][d8] = *(const uint4*)pk;
        }
    }
    __syncthreads();   // PEsh visible

    f32x4 O[2][4];
#pragma unroll
    for (int s = 0; s < 2; ++s)
#pragma unroll
        for (int dt = 0; dt < 4; ++dt)
#pragma unroll
            for (int r = 0; r < 4; ++r)
                O[s][dt][r] = bf2f(Pl[hh][(ww + 2 * s) * 16 + quad * 4 + r][dt * 16 + l15]);

#pragma unroll
    for (int s = 0; s < 2; ++s) {
#pragma unroll
        for (int r = 0; r < 4; ++r) {
            float mx = -1e30f;
#pragma unroll
            for (int mt = 0; mt < 4; ++mt) { S[s][mt][r] *= SCALE; mx = fmaxf(mx, S[s][mt][r]); }
            mx = fmaxf(mx, __shfl_xor(mx, 1));
            mx = fmaxf(mx, __shfl_xor(mx, 2));
            mx = fmaxf(mx, __shfl_xor(mx, 4));
            mx = fmaxf(mx, __shfl_xor(mx, 8));
            float sum = 0.f;
#pragma unroll
            for (int mt = 0; mt < 4; ++mt) { float e = __expf(S[s][mt][r] - mx); S[s][mt][r] = e; sum += e; }
            sum += __shfl_xor(sum, 1);
            sum += __shfl_xor(sum, 2);
            sum += __shfl_xor(sum, 4);
            sum += __shfl_xor(sum, 8);
            float inv = 1.f / sum;
#pragma unroll
            for (int mt = 0; mt < 4; ++mt) S[s][mt][r] *= inv;
        }
    }
    __syncthreads();   // all PEsh reads done

#pragma unroll
    for (int s = 0; s < 2; ++s)
#pragma unroll
        for (int r = 0; r < 4; ++r) {
            int n = (ww + 2 * s) * 16 + quad * 4 + r;
#pragma unroll
            for (int mt = 0; mt < 4; ++mt)
                Pl[hh][n][mt * 16 + l15] = f2bf(S[s][mt][r]);
        }
    __syncthreads();   // Pl visible

#pragma unroll
    for (int ks = 0; ks < 2; ++ks) {
        bf16x8 fp[2], fv[4];
#pragma unroll
        for (int s = 0; s < 2; ++s)
            fp[s] = *(const bf16x8*)&Pl[hh][(ww + 2 * s) * 16 + l15][ks * 32 + quad * 8];
#pragma unroll
        for (int dt = 0; dt < 4; ++dt)
            fv[dt] = *(const bf16x8*)&Vt[hh][dt * 16 + l15][ks * 32 + quad * 8];
#pragma unroll
        for (int s = 0; s < 2; ++s)
#pragma unroll
            for (int dt = 0; dt < 4; ++dt)
                O[s][dt] = __builtin_amdgcn_mfma_f32_16x16x32_bf16(fp[s], fv[dt], O[s][dt], 0, 0, 0);
    }
#pragma unroll
    for (int s = 0; s < 2; ++s) {
#pragma unroll
        for (int r = 0; r < 4; ++r) {
            int n = (ww + 2 * s) * 16 + quad * 4 + r;
            ushort* dst = o_out + (size_t)(b * 64 + n) * 256 + h * 64;
#pragma unroll
            for (int dt = 0; dt < 4; ++dt)
                dst[dt * 16 + l15] = f2bf(O[s][dt][r]);
        }
    }
}

// ---------------- scalar attention (used for K=4) ----------------
template<int K>
__global__ __launch_bounds__(256) void attn_kernel(
    const ushort* __restrict__ qkv,
    const float* __restrict__ pe_w,
    const float* __restrict__ pe_b,
    ushort* __restrict__ o_out)
{
    constexpr int NSP = K * K;
    constexpr float SCALE = 0.17677669529663687f;
    __shared__ float q_s[32][NSP];
    __shared__ float k_s[32][NSP];
    __shared__ float v_s[64][NSP + 1];
    __shared__ float S[NSP][NSP + 1];
    const int tid = threadIdx.x;
    const int h = blockIdx.x & 3;
    const int b = blockIdx.x >> 2;
    {
        int n0 = tid >> 4;
        int rr = (tid & 15) * 8;
        for (int nb = 0; nb < NSP; nb += 16) {
            int n = nb + n0;
            const ushort* src = qkv + (size_t)(b * NSP + n) * 512 + h * 128 + rr;
            uint4 pk = *(const uint4*)src;
            ushort us[8];
            *(uint4*)us = pk;
#pragma unroll
            for (int j = 0; j < 8; ++j) {
                int r = rr + j;
                float f = bf2f(us[j]);
                if (r < 32) q_s[r][n] = f * SCALE;
                else if (r < 64) k_s[r - 32][n] = f;
                else v_s[r - 64][n] = f;
            }
        }
    }
    __syncthreads();
    for (int idx = tid; idx < NSP * NSP; idx += 256) {
        int n = idx / NSP, m = idx % NSP;
        float a = 0.f;
#pragma unroll
        for (int d = 0; d < 32; ++d) a += q_s[d][n] * k_s[d][m];
        S[n][m] = a;
    }
    __syncthreads();
    for (int n = tid; n < NSP; n += 256) {
        float mx = -1e30f;
        for (int m = 0; m < NSP; ++m) mx = fmaxf(mx, S[n][m]);
        float sum = 0.f;
        for (int m = 0; m < NSP; ++m) { float e = __expf(S[n][m] - mx); S[n][m] = e; sum += e; }
        float inv = 1.f / sum;
        for (int m = 0; m < NSP; ++m) S[n][m] *= inv;
    }
    __syncthreads();
    for (int idx = tid; idx < 64 * NSP; idx += 256) {
        int d = idx & 63, n = idx >> 6;
        float a = 0.f;
        for (int m = 0; m < NSP; ++m) a += v_s[d][m] * S[n][m];
        int c = h * 64 + d;
        int p = n / K, q = n % K;
        float pe = pe_b[c];
        const float* wc = pe_w + c * 9;
#pragma unroll
    for (int dp = -1; dp <= 1; ++dp) {
#pragma unroll
            for (int dq = -1; dq <= 1; ++dq) {
                int pp = p + dp, qq = q + dq;
                if (pp >= 0 && pp < K && qq >= 0 && qq < K)
                    pe += wc[(dp + 1) * 3 + (dq + 1)] * v_s[d][pp * K + qq];
            }
        }
        o_out[(size_t)(b * NSP + n) * 256 + c] = f2bf(a + pe);
    }
}

// ---------------- final: out = (x + fold8(s8) + fold4(s4)) / 3 ----------------
__global__ __launch_bounds__(256) void final_kernel(
    const float* __restrict__ x,
    const ushort* __restrict__ s8,
    const ushort* __restrict__ s4,
    float* __restrict__ out)
{
    const int c2 = blockIdx.x & 255;
    const int g  = blockIdx.x >> 8;
    const ushort* s8g = s8 + (size_t)g * (256 * 64 * 225);
    const ushort* s4g = s4 + (size_t)g * (256 * 16 * 256);
    const float third = 1.f / 3.f;
#pragma unroll 2
    for (int it = 0; it < 16; ++it) {
        int pix = it * 256 + threadIdx.x;       // h*64 + w
        int h = pix >> 6, w = pix & 63;
        int f4 = ((((c2 * 4 + (h & 3)) * 4 + (w & 3)) * 16 + (h >> 2)) * 16) + (w >> 2);
        float v4 = bf2f(s4g[f4]);
        int lh_lo = (h >= 8) ? ((h - 4) >> 2) : 0, lh_hi = min(14, h >> 2);
        int lw_lo = (w >= 8) ? ((w - 4) >> 2) : 0, lw_hi = min(14, w >> 2);
        float v8 = 0.f;
        for (int lh2 = lh_lo; lh2 <= lh_hi; ++lh2) {
            int p2 = h - lh2 * 4;
            for (int lw2 = lw_lo; lw2 <= lw_hi; ++lw2) {
                int q2 = w - lw2 * 4;
                int f8 = (((c2 * 8 + p2) * 8 + q2) * 15 + lh2) * 15 + lw2;
                v8 += bf2f(s8g[f8]);
            }
        }
        float inv = 1.f / (float)((lh_hi - lh_lo + 1) * (lw_hi - lw_lo + 1));
        size_t off = ((size_t)(g * 256 + c2)) * 4096 + pix;
        out[off] = (x[off] + v8 * inv + v4) * third;
    }
}

extern "C" void kernel_launch(void* const* d_in, const int* in_sizes, int n_in,
                              void* d_out, int out_size, void* d_ws, size_t ws_size,
                              hipStream_t stream)
{
    const float* x      = (const float*)d_in[0];
    const float* qkv_w  = (const float*)d_in[1];
    const float* qkv_b  = (const float*)d_in[2];
    const float* proj_w = (const float*)d_in[3];
    const float* proj_b = (const float*)d_in[4];
    const float* apw    = (const float*)d_in[5];
    const float* apb    = (const float*)d_in[6];
    const float* dpw    = (const float*)d_in[7];
    const float* dpb    = (const float*)d_in[8];
    float* out = (float*)d_out;

    // Workspace: s8 59 + s4 16.8 + y 29.5 + q 59 + w 0.4 + B(bf16) 17.3 = 182.1 MB
    const size_t S8_B = 8ull * 225 * 256 * 64 * 2;
    const size_t S4_B = 8ull * 256 * 256 * 16 * 2;
    const size_t Y_B  = 4ull * 14400 * 256 * 2;
    const size_t Q_B  = 4ull * 14400 * 512 * 2;
    const size_t W_B  = (512ull * 256 + 256ull * 256) * 2;
    const size_t B_B  = 8ull * 65 * 65 * 256 * 2;
    if (ws_size < S8_B + S4_B + Y_B + Q_B + W_B + B_B) {
        hipMemsetAsync(d_out, 0x46, 4, stream);  // finite sentinel: ws too small
        return;
    }
    ushort* s8    = (ushort*)d_ws;
    ushort* s4    = s8 + S8_B / 2;
    ushort* ybuf  = s4 + S4_B / 2;
    ushort* qbuf  = ybuf + Y_B / 2;
    ushort* qw_bf = qbuf + Q_B / 2;
    ushort* pw_bf = qw_bf + 512 * 256;
    ushort* Bbuf  = (ushort*)((char*)d_ws + S8_B + S4_B + Y_B + Q_B + W_B);

    f2bf_kernel<<<128, 256, 0, stream>>>(qkv_w, qw_bf);
    f2bf_kernel<<<64, 256, 0, stream>>>(proj_w, pw_bf);
    box_kernel<<<8 * 65, 256, 0, stream>>>(x, Bbuf);   // all 8 images, once

    // K=8 chain (L=15), two halves of 4 images: 4*14400 = 57600 rows = 900 row-tiles
    for (int hf = 0; hf < 2; ++hf) {
        ushort* B_h = Bbuf + (size_t)hf * 4 * 65 * 65 * 256;
        ushort* s8_h = s8 + (size_t)hf * 4 * 225 * 256 * 64;
        pool_kernel<8, 15><<<4 * 225, 256, 0, stream>>>(B_h, dpw, dpb, ybuf);
        gemm_kernel<512, 0, 8, 15, 900><<<7232, 256, 0, stream>>>(ybuf, qw_bf, qkv_b, qbuf);
        attn8_mfma_kernel<<<900 * 2, 256, 0, stream>>>(qbuf, apw, apb, ybuf);
        gemm_kernel<256, 1, 8, 15, 900><<<3616, 256, 0, stream>>>(ybuf, pw_bf, proj_b, s8_h);
    }
    // K=4 chain (L=16), all 8 images: 8*4096 = 32768 rows = 512 row-tiles
    pool_kernel<4, 16><<<8 * 256, 256, 0, stream>>>(Bbuf, dpw, dpb, ybuf);
    gemm_kernel<512, 0, 4, 16, 512><<<4096, 256, 0, stream>>>(ybuf, qw_bf, qkv_b, qbuf);
    attn_kernel<4><<<8 * 256 * 4, 256, 0, stream>>>(qbuf, apw, apb, ybuf);
    gemm_kernel<256, 1, 4, 16, 512><<<2048, 256, 0, stream>>>(ybuf, pw_bf, proj_b, s4);

    final_kernel<<<2048, 256, 0, stream>>>(x, s8, s4, out);
}

// Round 13
// 479.211 us; speedup vs baseline: 1.0976x; 1.0080x over previous
//
#include <hip/hip_runtime.h>
#include <hip/hip_bf16.h>

typedef __bf16 bf16x8 __attribute__((ext_vector_type(8)));
typedef float  f32x4  __attribute__((ext_vector_type(4)));

#define DEV static __device__ __forceinline__

DEV float bf2f(ushort u) { unsigned x = ((unsigned)u) << 16; return __uint_as_float(x); }
DEV ushort f2bf(float f) {
    unsigned u = __float_as_uint(f);
    unsigned r = (u + 0x7FFFu + ((u >> 16) & 1u)) >> 16;  // RNE
    return (ushort)r;
}

// ---------------- fp32 -> bf16 weight conversion (one-time, tiny) ----------------
__global__ __launch_bounds__(256) void f2bf_kernel(
    const float* __restrict__ src, ushort* __restrict__ dst)
{
    int i = (blockIdx.x * 256 + threadIdx.x) * 4;
    float4 v = *(const float4*)(src + i);
    ushort4 o;
    o.x = f2bf(v.x); o.y = f2bf(v.y); o.z = f2bf(v.z); o.w = f2bf(v.w);
    *(ushort4*)(dst + i) = o;
}

// ---------------- attn-PE weight transpose: [256][9] fp32 -> [9][256] bf16 ----------------
__global__ __launch_bounds__(256) void pe_prep_kernel(
    const float* __restrict__ apw, ushort* __restrict__ wt)
{
    int i = blockIdx.x * 256 + threadIdx.x;
    if (i < 9 * 256) {
        int tap = i >> 8, c = i & 255;
        wt[i] = f2bf(apw[c * 9 + tap]);
    }
}

// ---------------- box filter: B[g][br][bc][256] bf16, br,bc in [0,65) ----------------
__global__ __launch_bounds__(256) void box_kernel(
    const float* __restrict__ x,   // [8][256][64][64] fp32
    ushort* __restrict__ B)        // [8][65][65][256] bf16
{
    int br = blockIdx.x % 65; int g = blockIdx.x / 65;
    const float* xg = x + (size_t)g * 256 * 4096;
    ushort* Bg = B + (size_t)g * 65 * 65 * 256;
    const int r0 = max(br - 1, 0) * 64;
    const int r1 = min(br, 63) * 64;
    __shared__ float s[128][65];
    const int wl = threadIdx.x & 63, cq = threadIdx.x >> 6;   // load mapping
    const int c2 = threadIdx.x & 127, bh = threadIdx.x >> 7;  // store mapping
    for (int half = 0; half < 2; ++half) {
#pragma unroll 4
        for (int it = 0; it < 32; ++it) {
            int cl_ = it * 4 + cq;
            const float* xp = xg + (size_t)(half * 128 + cl_) * 4096;
            s[cl_][wl] = xp[r0 + wl] + xp[r1 + wl];
        }
        __syncthreads();
        for (int bc = bh; bc < 65; bc += 2) {
            float v = 0.25f * (s[c2][max(bc - 1, 0)] + s[c2][min(bc, 63)]);
            Bg[((size_t)br * 65 + bc) * 256 + half * 128 + c2] = f2bf(v);
        }
        __syncthreads();
    }
}

// ---------------- pool gather + depthwise 3x3 + residual ----------------
template<int K, int L>
__global__ __launch_bounds__(256) void pool_kernel(
    const ushort* __restrict__ B,   // [8][65][65][256] bf16
    const float* __restrict__ w9,   // [256][9] fp32
    const float* __restrict__ bias, // [256] fp32
    ushort* __restrict__ y)         // bf16 out
{
    constexpr int HF = K / 2;
    const int pk = blockIdx.x;
    const int lw = pk % L; int t = pk / L; const int lh = t % L; const int g = t / L;
    const int c = threadIdx.x;
    const ushort* Bg = B + (size_t)g * 65 * 65 * 256 + c;
    float pool[K][K];
#pragma unroll
    for (int p = 0; p < K; ++p) {
        const int br = lh * 4 + p + (p >= HF ? 1 : 0);
#pragma unroll
        for (int q = 0; q < K; ++q) {
            const int bc = lw * 4 + q + (q >= HF ? 1 : 0);
            pool[p][q] = bf2f(Bg[((size_t)br * 65 + bc) * 256]);
        }
    }
    float wv[9];
#pragma unroll
    for (int i = 0; i < 9; ++i) wv[i] = w9[c * 9 + i];
    const float bv = bias[c];
    ushort* yp = y + (size_t)pk * (K * K) * 256 + c;
#pragma unroll
    for (int p = 0; p < K; ++p) {
#pragma unroll
        for (int q = 0; q < K; ++q) {
            float a = pool[p][q] + bv;   // residual + conv bias
#pragma unroll
            for (int dp = -1; dp <= 1; ++dp) {
#pragma unroll
                for (int dq = -1; dq <= 1; ++dq) {
                    int pp = p + dp, qq = q + dq;
                    if (pp >= 0 && pp < K && qq >= 0 && qq < K)
                        a += wv[(dp + 1) * 3 + (dq + 1)] * pool[pp][qq];
                }
            }
            yp[(p * K + q) * 256] = f2bf(a);
        }
    }
}

// ---------------- GEMM 64x64 tiles, XCD-aware swizzle + LDS XOR swizzle ----------------
template<int OC, int EPI, int K, int L, int RT>
__global__ __launch_bounds__(256) void gemm_kernel(
    const ushort* __restrict__ act,  // [rows][256] bf16
    const ushort* __restrict__ w,    // [OC][256]  bf16
    const float* __restrict__ bias,  // [OC] fp32
    ushort* __restrict__ out_bf)
{
    __shared__ __attribute__((aligned(16))) ushort As[64][40];
    __shared__ __attribute__((aligned(16))) ushort Ws[64][40];
    constexpr int NT = OC / 64;
    const int id  = blockIdx.x;
    const int xc  = id & 7;
    const int ctb = (id >> 3) % NT;
    const int tt  = id / (8 * NT);
    const int rowt = tt * 8 + xc;
    if (rowt >= RT) return;
    const int tid  = threadIdx.x;
    const int n0   = rowt * 64;
    const int ch0  = ctb * 64;
    const int wv   = tid >> 6, lane = tid & 63;
    const int l15  = lane & 15, quad = lane >> 4;
    const int ar   = tid >> 2, g = tid & 3;
    const int scol = ((g ^ (ar & 3)) * 8);     // swizzled staging col
    f32x4 acc[4] = {};

    const ushort* aptr = act + (size_t)(n0 + ar) * 256 + g * 8;
    const ushort* wptr = w   + (size_t)(ch0 + ar) * 256 + g * 8;
    const int mrow = wv * 16 + l15;
    const int aswz = ((quad ^ (mrow & 3)) * 8);
    for (int k0 = 0; k0 < 256; k0 += 32) {
        *(uint4*)&As[ar][scol] = *(const uint4*)(aptr + k0);
        *(uint4*)&Ws[ar][scol] = *(const uint4*)(wptr + k0);
        __syncthreads();
        bf16x8 af = *(const bf16x8*)&As[mrow][aswz];
#pragma unroll
        for (int mt = 0; mt < 4; ++mt) {
            const int brow = mt * 16 + l15;
            bf16x8 bfv = *(const bf16x8*)&Ws[brow][((quad ^ (brow & 3)) * 8)];
            acc[mt] = __builtin_amdgcn_mfma_f32_16x16x32_bf16(af, bfv, acc[mt], 0, 0, 0);
        }
        __syncthreads();
    }
    const int rbase = wv * 16 + quad * 4;
#pragma unroll
    for (int mt = 0; mt < 4; ++mt) {
        int ch = ch0 + mt * 16 + l15;
        float bv = bias[ch];
#pragma unroll
        for (int r = 0; r < 4; ++r) {
            int n = n0 + rbase + r;
            float val = acc[mt][r] + bv;
            if (EPI == 0) {
                out_bf[(size_t)n * OC + ch] = f2bf(val);
            } else {
                constexpr int K2 = K * K;
                constexpr int LL = L * L;
                int b_g   = n >> (K == 8 ? 6 : 4);
                int pq    = n & (K2 - 1);
                int gl    = b_g / LL;
                int b_loc = b_g - gl * LL;
                int f = (b_loc * 256 + ch) * K2 + pq;
                out_bf[(size_t)gl * (256 * K2 * LL) + f] = f2bf(val);
            }
        }
    }
}

// ---------------- MFMA attention for K=8 (NSP=64): block = 1 patch, 2 heads ----------------
__global__ __launch_bounds__(256) void attn8_mfma_kernel(
    const ushort* __restrict__ qkv,  // [patches*64][512] bf16
    const ushort* __restrict__ wt,   // [9][256] bf16 (transposed attn-PE weights)
    const float* __restrict__ pe_b,  // [256] fp32
    ushort* __restrict__ o_out)      // [patches*64][256] bf16
{
    constexpr float SCALE = 0.17677669529663687f;  // 32^-0.5
    __shared__ __attribute__((aligned(16))) ushort Pl[2][64][72];  // PEsh, then P
    __shared__ __attribute__((aligned(16))) ushort Vt[2][64][72];
    __shared__ __attribute__((aligned(16))) ushort wsh[9][128];    // dwconv w, [tap][c-local] bf16
    __shared__ float bsh[128];
    const int tid  = threadIdx.x;
    const int lane = tid & 63;
    const int w    = tid >> 6;
    const int hh   = w >> 1, ww = w & 1;
    const int b    = blockIdx.x >> 1;
    const int hbase = (blockIdx.x & 1) * 2;
    const int cbase = hbase * 64;
    const int h    = hbase + hh;
    const int l15  = lane & 15, quad = lane >> 4;
    const ushort* base = qkv + (size_t)b * 64 * 512 + h * 128;

    // ---- stage dwconv weights (coalesced from preconverted [9][256] bf16 table)
    if (tid < 144) {
        int tap = tid / 16, cl8 = (tid & 15) * 8;
        *(uint4*)&wsh[tap][cl8] = *(const uint4*)&wt[tap * 256 + cbase + cl8];
    }
    if (tid < 128) bsh[tid] = pe_b[cbase + tid];

    {
        const int m = lane;
        const ushort* vsrc = base + (size_t)m * 512 + 64 + ww * 32;
        const int d0 = ww * 32;
#pragma unroll
        for (int t = 0; t < 4; ++t) {
            uint4 vv = *(const uint4*)(vsrc + t * 8);
            unsigned u[4] = {vv.x, vv.y, vv.z, vv.w};
#pragma unroll
            for (int e = 0; e < 4; ++e) {
                Vt[hh][d0 + t * 8 + e * 2][m]     = (ushort)(u[e] & 0xFFFF);
                Vt[hh][d0 + t * 8 + e * 2 + 1][m] = (ushort)(u[e] >> 16);
            }
        }
    }

    bf16x8 fq[2];
#pragma unroll
    for (int s = 0; s < 2; ++s) {
        int n = (ww + 2 * s) * 16 + l15;
        fq[s] = *(const bf16x8*)(base + (size_t)n * 512 + quad * 8);
    }
    f32x4 S[2][4];
#pragma unroll
    for (int mt = 0; mt < 4; ++mt) {
        int m = mt * 16 + l15;
        bf16x8 fk = *(const bf16x8*)(base + (size_t)m * 512 + 32 + quad * 8);
#pragma unroll
        for (int s = 0; s < 2; ++s) {
            f32x4 z = {0.f, 0.f, 0.f, 0.f};
            S[s][mt] = __builtin_amdgcn_mfma_f32_16x16x32_bf16(fq[s], fk, z, 0, 0, 0);
        }
    }
    __syncthreads();   // wsh, bsh, Vt visible

    // ---- PE pre-pass, tap-outer: weights unpacked 9x instead of 288x
    {
        const int d8  = (tid & 7) * 8;
        const int nb  = (tid >> 3) & 15;
        const int hh2 = tid >> 7;
        const int h2  = hbase + hh2;
        const int cl0 = hh2 * 64 + d8;
        const ushort* vbase = qkv + (size_t)b * 64 * 512 + h2 * 128 + 64 + d8;
        float pe[4][8];
#pragma unroll
        for (int e = 0; e < 8; ++e) {
            float pb = bsh[cl0 + e];
#pragma unroll
            for (int it = 0; it < 4; ++it) pe[it][e] = pb;
        }
#pragma unroll
        for (int tap = 0; tap < 9; ++tap) {
            const int dp = tap / 3 - 1, dq = tap % 3 - 1;
            uint4 wv4 = *(const uint4*)&wsh[tap][cl0];
            unsigned uw[4] = {wv4.x, wv4.y, wv4.z, wv4.w};
            float wlo[4], whi[4];
#pragma unroll
            for (int e2 = 0; e2 < 4; ++e2) {
                wlo[e2] = __uint_as_float(uw[e2] << 16);
                whi[e2] = __uint_as_float(uw[e2] & 0xFFFF0000u);
            }
#pragma unroll
            for (int it = 0; it < 4; ++it) {
                const int n = nb + 16 * it;
                const int pp = (n >> 3) + dp, qq = (n & 7) + dq;
                if (pp >= 0 && pp < 8 && qq >= 0 && qq < 8) {
                    uint4 vv = *(const uint4*)(vbase + (size_t)(pp * 8 + qq) * 512);
                    unsigned uv[4] = {vv.x, vv.y, vv.z, vv.w};
#pragma unroll
                    for (int e2 = 0; e2 < 4; ++e2) {
                        float vlo = __uint_as_float(uv[e2] << 16);
                        float vhi = __uint_as_float(uv[e2] & 0xFFFF0000u);
                        pe[it][2 * e2]     += wlo[e2] * vlo;
                        pe[it][2 * e2 + 1] += whi[e2] * vhi;
                    }
                }
            }
        }
#pragma unroll
        for (int it = 0; it < 4; ++it) {
            const int n = nb + 16 * it;
            ushort pk[8];
#pragma unroll
            for (int e = 0; e < 8; ++e) pk[e] = f2bf(pe[it][e]);
            *(uint4*)&Pl[hh2][n][d8] = *(const uint4*)pk;
        }
    }
    __syncthreads();   // PEsh visible

    f32x4 O[2][4];
#pragma unroll
    for (int s = 0; s < 2; ++s)
#pragma unroll
        for (int dt = 0; dt < 4; ++dt)
#pragma unroll
            for (int r = 0; r < 4; ++r)
                O[s][dt][r] = bf2f(Pl[hh][(ww + 2 * s) * 16 + quad * 4 + r][dt * 16 + l15]);

#pragma unroll
    for (int s = 0; s < 2; ++s) {
#pragma unroll
        for (int r = 0; r < 4; ++r) {
            float mx = -1e30f;
#pragma unroll
            for (int mt = 0; mt < 4; ++mt) { S[s][mt][r] *= SCALE; mx = fmaxf(mx, S[s][mt][r]); }
            mx = fmaxf(mx, __shfl_xor(mx, 1));
            mx = fmaxf(mx, __shfl_xor(mx, 2));
            mx = fmaxf(mx, __shfl_xor(mx, 4));
            mx = fmaxf(mx, __shfl_xor(mx, 8));
            float sum = 0.f;
#pragma unroll
            for (int mt = 0; mt < 4; ++mt) { float e = __expf(S[s][mt][r] - mx); S[s][mt][r] = e; sum += e; }
            sum += __shfl_xor(sum, 1);
            sum += __shfl_xor(sum, 2);
            sum += __shfl_xor(sum, 4);
            sum += __shfl_xor(sum, 8);
            float inv = 1.f / sum;
#pragma unroll
            for (int mt = 0; mt < 4; ++mt) S[s][mt][r] *= inv;
        }
    }
    __syncthreads();   // all PEsh reads done

#pragma unroll
    for (int s = 0; s < 2; ++s)
#pragma unroll
        for (int r = 0; r < 4; ++r) {
            int n = (ww + 2 * s) * 16 + quad * 4 + r;
#pragma unroll
            for (int mt = 0; mt < 4; ++mt)
                Pl[hh][n][mt * 16 + l15] = f2bf(S[s][mt][r]);
        }
    __syncthreads();   // Pl visible

#pragma unroll
    for (int ks = 0; ks < 2; ++ks) {
        bf16x8 fp[2], fv[4];
#pragma unroll
        for (int s = 0; s < 2; ++s)
            fp[s] = *(const bf16x8*)&Pl[hh][(ww + 2 * s) * 16 + l15][ks * 32 + quad * 8];
#pragma unroll
        for (int dt = 0; dt < 4; ++dt)
            fv[dt] = *(const bf16x8*)&Vt[hh][dt * 16 + l15][ks * 32 + quad * 8];
#pragma unroll
        for (int s = 0; s < 2; ++s)
#pragma unroll
            for (int dt = 0; dt < 4; ++dt)
                O[s][dt] = __builtin_amdgcn_mfma_f32_16x16x32_bf16(fp[s], fv[dt], O[s][dt], 0, 0, 0);
    }
#pragma unroll
    for (int s = 0; s < 2; ++s) {
#pragma unroll
        for (int r = 0; r < 4; ++r) {
            int n = (ww + 2 * s) * 16 + quad * 4 + r;
            ushort* dst = o_out + (size_t)(b * 64 + n) * 256 + h * 64;
#pragma unroll
            for (int dt = 0; dt < 4; ++dt)
                dst[dt * 16 + l15] = f2bf(O[s][dt][r]);
        }
    }
}

// ---------------- scalar attention (used for K=4) ----------------
template<int K>
__global__ __launch_bounds__(256) void attn_kernel(
    const ushort* __restrict__ qkv,
    const ushort* __restrict__ wt,   // [9][256] bf16
    const float* __restrict__ pe_b,
    ushort* __restrict__ o_out)
{
    constexpr int NSP = K * K;
    constexpr float SCALE = 0.17677669529663687f;
    __shared__ float q_s[32][NSP];
    __shared__ float k_s[32][NSP];
    __shared__ float v_s[64][NSP + 1];
    __shared__ float S[NSP][NSP + 1];
    const int tid = threadIdx.x;
    const int h = blockIdx.x & 3;
    const int b = blockIdx.x >> 2;
    {
        int n0 = tid >> 4;
        int rr = (tid & 15) * 8;
        for (int nb = 0; nb < NSP; nb += 16) {
            int n = nb + n0;
            const ushort* src = qkv + (size_t)(b * NSP + n) * 512 + h * 128 + rr;
            uint4 pk = *(const uint4*)src;
            ushort us[8];
            *(uint4*)us = pk;
#pragma unroll
            for (int j = 0; j < 8; ++j) {
                int r = rr + j;
                float f = bf2f(us[j]);
                if (r < 32) q_s[r][n] = f * SCALE;
                else if (r < 64) k_s[r - 32][n] = f;
                else v_s[r - 64][n] = f;
            }
        }
    }
    __syncthreads();
    for (int idx = tid; idx < NSP * NSP; idx += 256) {
        int n = idx / NSP, m = idx % NSP;
        float a = 0.f;
#pragma unroll
        for (int d = 0; d < 32; ++d) a += q_s[d][n] * k_s[d][m];
        S[n][m] = a;
    }
    __syncthreads();
    for (int n = tid; n < NSP; n += 256) {
        float mx = -1e30f;
        for (int m = 0; m < NSP; ++m) mx = fmaxf(mx, S[n][m]);
        float sum = 0.f;
        for (int m = 0; m < NSP; ++m) { float e = __expf(S[n][m] - mx); S[n][m] = e; sum += e; }
        float inv = 1.f / sum;
        for (int m = 0; m < NSP; ++m) S[n][m] *= inv;
    }
    __syncthreads();
    for (int idx = tid; idx < 64 * NSP; idx += 256) {
        int d = idx & 63, n = idx >> 6;
        float a = 0.f;
        for (int m = 0; m < NSP; ++m) a += v_s[d][m] * S[n][m];
        int c = h * 64 + d;
        int p = n / K, q = n % K;
        float pe = pe_b[c];
#pragma unroll
        for (int dp = -1; dp <= 1; ++dp) {
#pragma unroll
            for (int dq = -1; dq <= 1; ++dq) {
                int pp = p + dp, qq = q + dq;
                if (pp >= 0 && pp < K && qq >= 0 && qq < K)
                    pe += bf2f(wt[((dp + 1) * 3 + (dq + 1)) * 256 + c]) * v_s[d][pp * K + qq];
            }
        }
        o_out[(size_t)(b * NSP + n) * 256 + c] = f2bf(a + pe);
    }
}

// ---------------- final: out = (x + fold8(s8) + fold4(s4)) / 3 ----------------
__global__ __launch_bounds__(256) void final_kernel(
    const float* __restrict__ x,
    const ushort* __restrict__ s8,
    const ushort* __restrict__ s4,
    float* __restrict__ out)
{
    const int c2 = blockIdx.x & 255;
    const int g  = blockIdx.x >> 8;
    const ushort* s8g = s8 + (size_t)g * (256 * 64 * 225);
    const ushort* s4g = s4 + (size_t)g * (256 * 16 * 256);
    const float third = 1.f / 3.f;
#pragma unroll 2
    for (int it = 0; it < 16; ++it) {
        int pix = it * 256 + threadIdx.x;       // h*64 + w
        int h = pix >> 6, w = pix & 63;
        int f4 = ((((c2 * 4 + (h & 3)) * 4 + (w & 3)) * 16 + (h >> 2)) * 16) + (w >> 2);
        float v4 = bf2f(s4g[f4]);
        int lh_lo = (h >= 8) ? ((h - 4) >> 2) : 0, lh_hi = min(14, h >> 2);
        int lw_lo = (w >= 8) ? ((w - 4) >> 2) : 0, lw_hi = min(14, w >> 2);
        float v8 = 0.f;
        for (int lh2 = lh_lo; lh2 <= lh_hi; ++lh2) {
            int p2 = h - lh2 * 4;
            for (int lw2 = lw_lo; lw2 <= lw_hi; ++lw2) {
                int q2 = w - lw2 * 4;
                int f8 = (((c2 * 8 + p2) * 8 + q2) * 15 + lh2) * 15 + lw2;
                v8 += bf2f(s8g[f8]);
            }
        }
        float inv = 1.f / (float)((lh_hi - lh_lo + 1) * (lw_hi - lw_lo + 1));
        size_t off = ((size_t)(g * 256 + c2)) * 4096 + pix;
        out[off] = (x[off] + v8 * inv + v4) * third;
    }
}

extern "C" void kernel_launch(void* const* d_in, const int* in_sizes, int n_in,
                              void* d_out, int out_size, void* d_ws, size_t ws_size,
                              hipStream_t stream)
{
    const float* x      = (const float*)d_in[0];
    const float* qkv_w  = (const float*)d_in[1];
    const float* qkv_b  = (const float*)d_in[2];
    const float* proj_w = (const float*)d_in[3];
    const float* proj_b = (const float*)d_in[4];
    const float* apw    = (const float*)d_in[5];
    const float* apb    = (const float*)d_in[6];
    const float* dpw    = (const float*)d_in[7];
    const float* dpb    = (const float*)d_in[8];
    float* out = (float*)d_out;

    // Workspace: s8 59 + s4 16.8 + y 29.5 + q 59 + w 0.4 + B(bf16) 17.3 = 182.1 MB
    const size_t S8_B = 8ull * 225 * 256 * 64 * 2;
    const size_t S4_B = 8ull * 256 * 256 * 16 * 2;
    const size_t Y_B  = 4ull * 14400 * 256 * 2;
    const size_t Q_B  = 4ull * 14400 * 512 * 2;
    const size_t W_B  = (512ull * 256 + 256ull * 256 + 9ull * 256) * 2;
    const size_t B_B  = 8ull * 65 * 65 * 256 * 2;
    if (ws_size < S8_B + S4_B + Y_B + Q_B + W_B + B_B) {
        hipMemsetAsync(d_out, 0x46, 4, stream);  // finite sentinel: ws too small
        return;
    }
    ushort* s8    = (ushort*)d_ws;
    ushort* s4    = s8 + S8_B / 2;
    ushort* ybuf  = s4 + S4_B / 2;
    ushort* qbuf  = ybuf + Y_B / 2;
    ushort* qw_bf = qbuf + Q_B / 2;
    ushort* pw_bf = qw_bf + 512 * 256;
    ushort* wt    = pw_bf + 256 * 256;
    ushort* Bbuf  = (ushort*)((char*)d_ws + S8_B + S4_B + Y_B + Q_B + W_B);

    f2bf_kernel<<<128, 256, 0, stream>>>(qkv_w, qw_bf);
    f2bf_kernel<<<64, 256, 0, stream>>>(proj_w, pw_bf);
    pe_prep_kernel<<<9, 256, 0, stream>>>(apw, wt);
    box_kernel<<<8 * 65, 256, 0, stream>>>(x, Bbuf);   // all 8 images, once

    // K=8 chain (L=15), two halves of 4 images: 4*14400 = 57600 rows = 900 row-tiles
    for (int hf = 0; hf < 2; ++hf) {
        ushort* B_h = Bbuf + (size_t)hf * 4 * 65 * 65 * 256;
        ushort* s8_h = s8 + (size_t)hf * 4 * 225 * 256 * 64;
        pool_kernel<8, 15><<<4 * 225, 256, 0, stream>>>(B_h, dpw, dpb, ybuf);
        gemm_kernel<512, 0, 8, 15, 900><<<7232, 256, 0, stream>>>(ybuf, qw_bf, qkv_b, qbuf);
        attn8_mfma_kernel<<<900 * 2, 256, 0, stream>>>(qbuf, wt, apb, ybuf);
        gemm_kernel<256, 1, 8, 15, 900><<<3616, 256, 0, stream>>>(ybuf, pw_bf, proj_b, s8_h);
    }
    // K=4 chain (L=16), all 8 images: 8*4096 = 32768 rows = 512 row-tiles
    pool_kernel<4, 16><<<8 * 256, 256, 0, stream>>>(Bbuf, dpw, dpb, ybuf);
    gemm_kernel<512, 0, 4, 16, 512><<<4096, 256, 0, stream>>>(ybuf, qw_bf, qkv_b, qbuf);
    attn_kernel<4><<<8 * 256 * 4, 256, 0, stream>>>(qbuf, wt, apb, ybuf);
    gemm_kernel<256, 1, 4, 16, 512><<<2048, 256, 0, stream>>>(ybuf, pw_bf, proj_b, s4);

    final_kernel<<<2048, 256, 0, stream>>>(x, s8, s4, out);
}